// Round 5
// baseline (65.058 us; speedup 1.0000x reference)
//
#include <hip/hip_runtime.h>
#include <stdint.h>

#define BB 8
#define NN 2048
#define CC 128
#define OO 128

typedef __attribute__((ext_vector_type(8))) short bf16x8;
typedef __attribute__((ext_vector_type(4))) float f32x4;
typedef __attribute__((ext_vector_type(4))) int i32x4;
typedef __attribute__((ext_vector_type(4))) unsigned short u16x4;
typedef unsigned int u32;
typedef unsigned short u16;

__device__ __forceinline__ u16 f2bf(float f) {
    union { float f; u32 u; } v; v.f = f;
    u32 r = v.u + 0x7FFFu + ((v.u >> 16) & 1u);
    return (u16)(r >> 16);
}

// ---------------------------------------------------------------------------
// Kernel 0: Wt[o][c] = bf16(W_lin[c][o]).  16 blocks x 256 thr (tiny).
// ---------------------------------------------------------------------------
__global__ __launch_bounds__(256) void wt_kernel(
    const float* __restrict__ W_lin, u16* __restrict__ Wt)
{
    __shared__ float ws2[8][132];
    const int t = threadIdx.x, o0 = blockIdx.x * 8;
    f32x4 v = *(const f32x4*)(W_lin + (t >> 1) * OO + o0 + (t & 1) * 4);
    #pragma unroll
    for (int e = 0; e < 4; ++e) ws2[(t & 1) * 4 + e][t >> 1] = v[e];
    __syncthreads();
    const int oo = t >> 5, c0 = (t & 31) * 4;
    f32x4 u = *(const f32x4*)&ws2[oo][c0];
    u16x4 h;
    #pragma unroll
    for (int e = 0; e < 4; ++e) h[e] = f2bf(u[e]);
    *(u16x4*)(Wt + (size_t)(o0 + oo) * CC + c0) = h;
}

// ---------------------------------------------------------------------------
// Kernel 1: precompute via MFMA, no LDS.
//   sj[b][n] = x·w1 + b_fc ; sk[b][n] = x·w2 (f32); Yt = bf16((x@W_lin)^T)
// ---------------------------------------------------------------------------
__global__ __launch_bounds__(256) void precompute_kernel(
    const float* __restrict__ x, const float* __restrict__ W_fc,
    const float* __restrict__ b_fc, const u16* __restrict__ Wt,
    float* __restrict__ sj, float* __restrict__ sk, u16* __restrict__ Yt)
{
    const int t = threadIdx.x, l = t & 63, w = t >> 6;
    const int sl = l & 15, g = l >> 4;
    const int b  = blockIdx.x >> 6;
    const int k0 = (blockIdx.x & 63) << 5;
    const int mt = w & 1, nb = (w >> 1) << 2;
    const int row = k0 + mt * 16 + sl;
    const float* xr = x + ((size_t)(b * NN + row) << 7);

    bf16x8 a[4];
    float p1 = 0.f, p2 = 0.f;
    #pragma unroll
    for (int ks = 0; ks < 4; ++ks) {
        f32x4 lo4 = *(const f32x4*)(xr + ks * 32 + g * 8);
        f32x4 hi4 = *(const f32x4*)(xr + ks * 32 + g * 8 + 4);
        f32x4 w1l = *(const f32x4*)(W_fc + ks * 32 + g * 8);
        f32x4 w1h = *(const f32x4*)(W_fc + ks * 32 + g * 8 + 4);
        f32x4 w2l = *(const f32x4*)(W_fc + CC + ks * 32 + g * 8);
        f32x4 w2h = *(const f32x4*)(W_fc + CC + ks * 32 + g * 8 + 4);
        bf16x8 av;
        #pragma unroll
        for (int e = 0; e < 4; ++e) {
            p1 += lo4[e] * w1l[e] + hi4[e] * w1h[e];
            p2 += lo4[e] * w2l[e] + hi4[e] * w2h[e];
            av[e]     = (short)f2bf(lo4[e]);
            av[e + 4] = (short)f2bf(hi4[e]);
        }
        a[ks] = av;
    }
    p1 += __shfl_xor(p1, 16); p1 += __shfl_xor(p1, 32);
    p2 += __shfl_xor(p2, 16); p2 += __shfl_xor(p2, 32);
    if (w < 2 && g == 0) {
        sj[b * NN + row] = p1 + b_fc[0];
        sk[b * NN + row] = p2;
    }

    f32x4 acc[4];
    #pragma unroll
    for (int i = 0; i < 4; ++i) acc[i] = (f32x4){0.f, 0.f, 0.f, 0.f};
    #pragma unroll
    for (int i = 0; i < 4; ++i) {
        const u16* wp = Wt + (size_t)((nb + i) * 16 + sl) * CC;
        #pragma unroll
        for (int ks = 0; ks < 4; ++ks) {
            bf16x8 bv = *(const bf16x8*)(wp + ks * 32 + g * 8);
            acc[i] = __builtin_amdgcn_mfma_f32_16x16x32_bf16(a[ks], bv, acc[i], 0, 0, 0);
        }
    }
    #pragma unroll
    for (int i = 0; i < 4; ++i) {
        const int o = (nb + i) * 16 + sl;
        u16x4 h;
        #pragma unroll
        for (int e = 0; e < 4; ++e) h[e] = f2bf(acc[i][e]);
        *(u16x4*)(Yt + (size_t)(b * OO + o) * NN + k0 + mt * 16 + g * 4) = h;
    }
}

// ---------------------------------------------------------------------------
// Kernel 2: main fused aggregation — register-B, single-barrier pipeline.
// Facts driving this structure (R4 profile): steady-state adj is L3-resident
// (FETCH ~0.4MB) and Yt[b] (512KB, XCD-pinned) is L2-resident -> kernel is
// LATENCY-bound, not HBM-bound. So: no LDS staging of Y at all. Per tile:
//   - B-frags loaded straight from L2 Yt into regs (8 x 16B/lane; each
//     16-lane group covers whole 64B lines)
//   - P(kt+1) sigmoid from register-prefetched adj/sk (static E/O sets,
//     1-tile lead ~600cyc), written to DOUBLE-BUFFERED pbuf
//   - MFMA(kt) reads pbuf[kt&1] (XOR-swizzled, conflict-free)
//   - ONE lgkmcnt(0)+barrier per tile: write parity != read parity inside
//     the body; the end barrier fences reads of parity p from the next
//     body's write to p.
// LDS = 16.5KB (was 72.5); no gl_lds, no manual vmcnt.
// 512 blocks (b = bid&7 XCD-pinned), 256 thr, j-tile 32.
// ---------------------------------------------------------------------------
__global__ __launch_bounds__(256, 2) void graphconv_main(
    const int* __restrict__ adj, const float* __restrict__ sj,
    const float* __restrict__ sk, const u16* __restrict__ Yt,
    const float* __restrict__ b_lin, float* __restrict__ out)
{
    __shared__ __align__(16) u16 pbuf[2][4096];   // [parity][32 j x 16 chunks x 8]
    __shared__ float Sld[32];

    const int t  = threadIdx.x;
    const int l  = t & 63, w = t >> 6;
    const int sw = l & 15, kg = l >> 4;
    const int b  = blockIdx.x & 7;
    const int j0 = (int)(blockIdx.x >> 3) << 5;

    // P-phase mapping: thread -> row r (32 rows), 16 consecutive k at (t&7)*16
    const int r  = t >> 3;
    const int ks = (t & 7) << 4;
    const float sjr = sj[b * NN + j0 + r];
    const int*   arow = adj + ((size_t)b * NN + j0 + r) * NN + ks;
    const float* skp  = sk + b * NN + ks;

    // B-frag bases: lane sw -> o row (js via base0/1 is os here), kg -> k-group
    const u16* ybase0 = Yt + (size_t)(b * OO + w * 32 + sw) * NN + kg * 8;
    const u16* ybase1 = Yt + (size_t)(b * OO + w * 32 + 16 + sw) * NN + kg * 8;

    f32x4 acc00 = {0,0,0,0}, acc01 = {0,0,0,0};
    f32x4 acc10 = {0,0,0,0}, acc11 = {0,0,0,0};
    float psum = 0.f;

    // adj/sk register sets (static E/O double-buffer, no rotation moves)
    i32x4 aE[4], aO[4]; f32x4 sE[4], sO[4];
    #pragma unroll
    for (int q = 0; q < 4; ++q) {
        aE[q] = *(const i32x4*)(arow + q * 4);
        sE[q] = *(const f32x4*)(skp + q * 4);
    }
    #pragma unroll
    for (int q = 0; q < 4; ++q) {
        aO[q] = *(const i32x4*)(arow + 128 + q * 4);
        sO[q] = *(const f32x4*)(skp + 128 + q * 4);
    }

// sigmoid + pack + store to pbuf[PAR] for the tile whose adj/sk are in AV/SV
#define PSTORE(AV, SV, PAR)                                                   \
    {                                                                         \
        bf16x8 hv0, hv1;                                                      \
        _Pragma("unroll")                                                     \
        for (int q = 0; q < 4; ++q) {                                         \
            _Pragma("unroll")                                                 \
            for (int e = 0; e < 4; ++e) {                                     \
                float z  = sjr + SV[q][e];                                    \
                float sg = __builtin_amdgcn_rcpf(1.0f + __expf(-z));          \
                float pv = AV[q][e] ? sg : 0.0f;                              \
                psum += pv;                                                   \
                if (q < 2) hv0[q * 4 + e]       = (short)f2bf(pv);            \
                else       hv1[(q - 2) * 4 + e] = (short)f2bf(pv);            \
            }                                                                 \
        }                                                                     \
        const int kcA = (t & 7) * 2;                                          \
        const int uA  = r * 16 + (kcA ^ (r & 15));                            \
        const int uB  = r * 16 + ((kcA + 1) ^ (r & 15));                      \
        *(bf16x8*)&pbuf[PAR][uA * 8] = hv0;                                   \
        *(bf16x8*)&pbuf[PAR][uB * 8] = hv1;                                   \
    }

    // prologue: P(0) -> pbuf[0]
    PSTORE(aE, sE, 0)
    asm volatile("s_waitcnt lgkmcnt(0)" ::: "memory");
    __builtin_amdgcn_s_barrier();
    asm volatile("" ::: "memory");

#define BODY(KT, AV, SV, AN, SN)                                              \
    {                                                                         \
        const int kt_ = (KT);                                                 \
        /* B-fragments for tile kt_ straight from L2-resident Yt */           \
        bf16x8 bfr0[4], bfr1[4];                                              \
        _Pragma("unroll")                                                     \
        for (int kk = 0; kk < 4; ++kk) {                                      \
            bfr0[kk] = *(const bf16x8*)(ybase0 + kt_ * 128 + kk * 32);        \
            bfr1[kk] = *(const bf16x8*)(ybase1 + kt_ * 128 + kk * 32);        \
        }                                                                     \
        /* P(kt_+1) from prefetched regs -> pbuf[(kt_+1)&1] */                \
        if (kt_ < 15) PSTORE(AV, SV, ((kt_ + 1) & 1))                         \
        /* adj/sk(kt_+2) prefetch into the just-freed set */                  \
        if (kt_ < 14) {                                                       \
            _Pragma("unroll")                                                 \
            for (int q = 0; q < 4; ++q) {                                     \
                AN[q] = *(const i32x4*)(arow + (kt_ + 2) * 128 + q * 4);      \
                SN[q] = *(const f32x4*)(skp  + (kt_ + 2) * 128 + q * 4);      \
            }                                                                 \
        }                                                                     \
        /* MFMA(kt_): A from pbuf[kt_&1], B from regs */                      \
        _Pragma("unroll")                                                     \
        for (int kk = 0; kk < 4; ++kk) {                                      \
            const int kc = kk * 4 + kg;                                       \
            bf16x8 af0 = *(const bf16x8*)&pbuf[kt_ & 1][(sw * 16 + (kc ^ sw)) * 8];        \
            bf16x8 af1 = *(const bf16x8*)&pbuf[kt_ & 1][((16 + sw) * 16 + (kc ^ sw)) * 8]; \
            acc00 = __builtin_amdgcn_mfma_f32_16x16x32_bf16(af0, bfr0[kk], acc00, 0, 0, 0);\
            acc01 = __builtin_amdgcn_mfma_f32_16x16x32_bf16(af0, bfr1[kk], acc01, 0, 0, 0);\
            acc10 = __builtin_amdgcn_mfma_f32_16x16x32_bf16(af1, bfr0[kk], acc10, 0, 0, 0);\
            acc11 = __builtin_amdgcn_mfma_f32_16x16x32_bf16(af1, bfr1[kk], acc11, 0, 0, 0);\
        }                                                                     \
        asm volatile("s_waitcnt lgkmcnt(0)" ::: "memory");                    \
        __builtin_amdgcn_s_barrier();                                         \
        asm volatile("" ::: "memory");                                        \
    }

    for (int m = 0; m < 8; ++m) {
        BODY(2 * m,     aO, sO, aE, sE)
        BODY(2 * m + 1, aE, sE, aO, sO)
    }
#undef BODY
#undef PSTORE

    // rowsum: 8 threads share a row -> 3-step shuffle reduce
    {
        float s = psum;
        s += __shfl_xor(s, 1); s += __shfl_xor(s, 2); s += __shfl_xor(s, 4);
        if ((l & 7) == 0) Sld[r] = s;
    }
    __syncthreads();

    // epilogue: scale by 1/rowsum, add bias, store f32
    #pragma unroll
    for (int js = 0; js < 2; ++js) {
        float rinv[4];
        #pragma unroll
        for (int i = 0; i < 4; ++i) rinv[i] = 1.0f / Sld[js * 16 + kg * 4 + i];
        const f32x4 a0 = js ? acc10 : acc00;
        const f32x4 a1 = js ? acc11 : acc01;
        #pragma unroll
        for (int os = 0; os < 2; ++os) {
            const int col = w * 32 + os * 16 + sw;
            const float bl = b_lin[col];
            const f32x4 av = os ? a1 : a0;
            #pragma unroll
            for (int i = 0; i < 4; ++i) {
                size_t row = (size_t)(b * NN + j0 + js * 16 + kg * 4 + i);
                out[row * OO + col] = av[i] * rinv[i] + bl;
            }
        }
    }
}

extern "C" void kernel_launch(void* const* d_in, const int* in_sizes, int n_in,
                              void* d_out, int out_size, void* d_ws, size_t ws_size,
                              hipStream_t stream) {
    const float* x     = (const float*)d_in[0];
    const int*   adj   = (const int*)d_in[1];
    const float* W_fc  = (const float*)d_in[2];
    const float* b_fc  = (const float*)d_in[3];
    const float* W_lin = (const float*)d_in[4];
    const float* b_lin = (const float*)d_in[5];
    float* out = (float*)d_out;

    // workspace: Yt (bf16, 4MB) | sj (64KB) | sk (64KB) | Wt (32KB)
    u16*   Yt = (u16*)d_ws;
    float* sj = (float*)((char*)d_ws + (size_t)BB * OO * NN * sizeof(u16));
    float* sk = sj + BB * NN;
    u16*   Wt = (u16*)(sk + BB * NN);

    wt_kernel<<<16, 256, 0, stream>>>(W_lin, Wt);
    precompute_kernel<<<512, 256, 0, stream>>>(x, W_fc, b_fc, Wt, sj, sk, Yt);
    graphconv_main<<<512, 256, 0, stream>>>(adj, sj, sk, Yt, b_lin, out);
}